// Round 8
// baseline (408.961 us; speedup 1.0000x reference)
//
#include <hip/hip_runtime.h>
#include <hip/hip_bf16.h>

#define Bb 16
#define Lq 2048
#define Hh 256
#define NLay 4
#define IND 40
#define OUTD 33

typedef unsigned int uint32;
typedef unsigned short ushort_t;

typedef short bf16x8 __attribute__((ext_vector_type(8)));
typedef float f32x4 __attribute__((ext_vector_type(4)));

__device__ __forceinline__ float sigmoidf_(float x) {
    return 1.0f / (1.0f + __expf(-x));
}
__device__ __forceinline__ float gelu_(float x) {
    float x2 = x * x;
    float u = x * fmaf(0.0713548162726f, x2, 1.5957691216057308f);
    return x * sigmoidf_(u);
}
__device__ __forceinline__ unsigned short f2bf(float f) {
    uint32 u = __float_as_uint(f);
    return (unsigned short)((u + 0x7fffu + ((u >> 16) & 1u)) >> 16);
}
__device__ __forceinline__ float bf2f(unsigned short s) {
    return __uint_as_float(((uint32)s) << 16);
}
__device__ __forceinline__ void gload16(const void* g, void* l) {
    __builtin_amdgcn_global_load_lds(
        (const __attribute__((address_space(1))) unsigned int*)g,
        (__attribute__((address_space(3))) unsigned int*)l, 16, 0, 0);
}

// ---------------- encoder ----------------
__global__ __launch_bounds__(256) void enc_kernel(const float* __restrict__ x,
                                                  const float* __restrict__ enc_w,
                                                  const float* __restrict__ enc_b,
                                                  float* __restrict__ h) {
    __shared__ float xs[8 * IND];
    int tid = threadIdx.x;
    int t0 = blockIdx.x * 8;
    for (int i = tid; i < 8 * IND; i += 256) xs[i] = x[t0 * IND + i];
    float w[IND];
    const float4* w4 = (const float4*)(enc_w + tid * IND);
#pragma unroll
    for (int c = 0; c < 10; ++c) {
        float4 v = w4[c];
        w[4 * c] = v.x; w[4 * c + 1] = v.y; w[4 * c + 2] = v.z; w[4 * c + 3] = v.w;
    }
    float bias = enc_b[tid];
    __syncthreads();
#pragma unroll
    for (int t = 0; t < 8; ++t) {
        float acc = bias;
#pragma unroll
        for (int i = 0; i < IND; ++i) acc = fmaf(xs[t * IND + i], w[i], acc);
        h[(size_t)(t0 + t) * Hh + tid] = acc;
    }
}

// ---------------- weight fp32->bf16 conversion ----------------
__global__ __launch_bounds__(256) void wconv_kernel(const float* __restrict__ w1,
                                                    const float* __restrict__ w2,
                                                    unsigned short* __restrict__ o) {
    int idx = blockIdx.x * 256 + threadIdx.x;
    for (int i = idx; i < 65536; i += 32768) {
        float4 a = ((const float4*)w1)[i];
        ushort4 u;
        u.x = f2bf(a.x); u.y = f2bf(a.y); u.z = f2bf(a.z); u.w = f2bf(a.w);
        ((ushort4*)o)[i] = u;
        float4 b4 = ((const float4*)w2)[i];
        ushort4 v;
        v.x = f2bf(b4.x); v.y = f2bf(b4.y); v.z = f2bf(b4.z); v.w = f2bf(b4.w);
        ((ushort4*)(o + 262144))[i] = v;
    }
}

// ---------------- layernorm + transpose (first layer only): h -> zT bf16 (chunk-swizzled) ----------------
__global__ __launch_bounds__(256) void lnt_kernel(const float* __restrict__ h,
                                                  const float* __restrict__ scale,
                                                  const float* __restrict__ bias,
                                                  uint32* __restrict__ zT_u) {
    __shared__ float T[32 * 260];
    __shared__ float musab[64];
    __shared__ float scb[512];
    int tid = threadIdx.x, lane = tid & 63, wv = tid >> 6;
    size_t t0 = (size_t)blockIdx.x * 32;
    int b = (int)(t0 >> 11);
    int tloc = (int)(t0 & 2047);
    scb[tid] = scale[tid];
    scb[256 + tid] = bias[tid];
#pragma unroll
    for (int p = 0; p < 8; ++p) {
        int idx = tid + p * 256;
        int r = idx >> 6, c4 = idx & 63;
        float4 v = *(const float4*)&h[(t0 + r) * Hh + c4 * 4];
        *(float4*)&T[r * 260 + c4 * 4] = v;
    }
    __syncthreads();
    for (int tok = wv; tok < 32; tok += 4) {
        float4 v = *(const float4*)&T[tok * 260 + lane * 4];
        float s = (v.x + v.y) + (v.z + v.w);
        float q = fmaf(v.x, v.x, fmaf(v.y, v.y, fmaf(v.z, v.z, v.w * v.w)));
#pragma unroll
        for (int m = 1; m < 64; m <<= 1) {
            s += __shfl_xor(s, m, 64);
            q += __shfl_xor(q, m, 64);
        }
        if (lane == 0) {
            float mu = s * (1.0f / 256.0f);
            float var = q * (1.0f / 256.0f) - mu * mu;
            musab[tok] = mu;
            musab[32 + tok] = rsqrtf(var + 1e-5f);
        }
    }
    __syncthreads();
#pragma unroll
    for (int j = 0; j < 16; ++j) {
        int hh = wv * 64 + j * 4 + (lane >> 4);
        int tp = lane & 15;
        float v0 = T[(2 * tp) * 260 + hh];
        float v1 = T[(2 * tp + 1) * 260 + hh];
        float m0 = musab[2 * tp], r0 = musab[32 + 2 * tp];
        float m1 = musab[2 * tp + 1], r1 = musab[33 + 2 * tp];
        float sc = scb[hh], bi = scb[256 + hh];
        float o0 = fmaf((v0 - m0) * r0, sc, bi);
        float o1 = fmaf((v1 - m1) * r1, sc, bi);
        uint32 pk = ((uint32)f2bf(o1) << 16) | (uint32)f2bf(o0);
        uint32 u = (uint32)((tloc >> 1) + tp);
        uint32 usw = (u & ~28u) | ((((u >> 2) & 7u) ^ ((u >> 5) & 7u)) << 2);
        zT_u[(size_t)(b * 256 + hh) * 1024 + usw] = pk;
    }
}

// ---------------- k1 (ALL LAYERS batched, LDS power table) ----------------
__global__ __launch_bounds__(256) void k1_kernel(const float* __restrict__ lre_p,
                                                 const float* __restrict__ lim_p,
                                                 const float* __restrict__ cre_p,
                                                 const float* __restrict__ cim_p,
                                                 const float* __restrict__ d_p,
                                                 const float* __restrict__ ls_p,
                                                 unsigned short* __restrict__ tv,
                                                 unsigned short* __restrict__ eb,
                                                 float* __restrict__ da64) {
    __shared__ float pwre[65 * 65];
    __shared__ float pwim[65 * 65];
    __shared__ float GrS[64], GiS[64], ks[64];
    int il = blockIdx.x >> 8;
    int h = blockIdx.x & 255;
    lre_p += (size_t)il * 16384; lim_p += (size_t)il * 16384;
    cre_p += (size_t)il * 16384; cim_p += (size_t)il * 16384;
    d_p += il * Hh; ls_p += il * Hh;
    tv += (size_t)il * 6291456;
    eb += (size_t)il * 2097152;
    da64 += (size_t)il * 32768;
    int tid = threadIdx.x;
    int lane = tid & 63, wv = tid >> 6;

    {
        int n = lane;
        float lre = lre_p[h * 64 + n], lim = lim_p[h * 64 + n];
        float cre = cre_p[h * 64 + n], cim = cim_p[h * 64 + n];
        float dt = expf(ls_p[h]);
        float a = lre * dt, th = lim * dt;
        float s1, c1;
        sincosf(th, &s1, &c1);
        float er1 = expf(a);
        float dre = er1 * c1, dim = er1 * s1;
        if (wv == 0) {
            float dAre = dre, dAim = dim;
            float inv = 1.0f / (lre * lre + lim * lim);
            float dBre = ((dAre - 1.0f) * lre + dAim * lim) * inv;
            float dBim = (dAim * lre - (dAre - 1.0f) * lim) * inv;
            GrS[n] = cre * dBre - cim * dBim;
            GiS[n] = cre * dBim + cim * dBre;
        }
        float m0 = (float)(wv * 16);
        float sb, cb;
        sincosf(m0 * th, &sb, &cb);
        float erb = expf(m0 * a);
        float pre = erb * cb, pim = erb * sb;
#pragma unroll
        for (int mm = 0; mm < 16; ++mm) {
            int m = wv * 16 + mm;
            pwre[m * 65 + n] = pre;
            pwim[m * 65 + n] = pim;
            float nr = pre * dre - pim * dim;
            float ni = pre * dim + pim * dre;
            pre = nr; pim = ni;
        }
        if (wv == 3) {
            pwre[64 * 65 + n] = pre;
            pwim[64 * 65 + n] = pim;
            da64[h * 128 + n] = pre;
            da64[h * 128 + 64 + n] = pim;
        }
    }
    __syncthreads();

    {
        int m = tid >> 2, s = tid & 3;
        float acc = 0.0f;
#pragma unroll
        for (int i = 0; i < 16; ++i) {
            int n2 = s * 16 + i;
            acc = fmaf(GrS[n2], pwre[m * 65 + n2], fmaf(-GiS[n2], pwim[m * 65 + n2], acc));
        }
        acc += __shfl_xor(acc, 1, 64);
        acc += __shfl_xor(acc, 2, 64);
        if (s == 0) ks[m] = 2.0f * acc;
    }
    __syncthreads();

    float dh = d_p[h];
    size_t basep = (size_t)h * 24576;
#pragma unroll
    for (int i2 = 0; i2 < 16; ++i2) {   // T' hi + lo
        int e = tid + i2 * 256;
        int l = e >> 6, j = e & 63;
        float v = (j < l) ? ks[l - j] : (j == l ? ks[0] + dh : 0.0f);
        int sj = (((j >> 3) ^ (l & 7)) << 3) | (j & 7);
        unsigned short hi = f2bf(v);
        tv[basep + l * 64 + sj] = hi;
        tv[basep + (64 + l) * 64 + sj] = f2bf(v - bf2f(hi));
    }
#pragma unroll
    for (int i2 = 0; i2 < 32; ++i2) {   // V' hi + lo
        int e = tid + i2 * 256;
        int part = e >> 12, n = (e >> 6) & 63, j = e & 63;
        int m = 63 - j;
        float pre = pwre[m * 65 + n], pim = pwim[m * 65 + n];
        float v = part ? fmaf(GrS[n], pim, GiS[n] * pre) : fmaf(GrS[n], pre, -GiS[n] * pim);
        int sj = (((j >> 3) ^ (n & 7)) << 3) | (j & 7);
        unsigned short hi = f2bf(v);
        tv[basep + (size_t)(128 + part * 64 + n) * 64 + sj] = hi;
        tv[basep + (size_t)(256 + part * 64 + n) * 64 + sj] = f2bf(v - bf2f(hi));
    }
#pragma unroll
    for (int i2 = 0; i2 < 32; ++i2) {   // E'
        int e = tid + i2 * 256;
        int l = e >> 7, k = e & 127;
        int n = k & 63, m = l + 1;
        float v = (k < 64) ? 2.0f * pwre[m * 65 + n] : -2.0f * pwim[m * 65 + n];
        eb[(size_t)h * 8192 + l * 128 + ((((k >> 3) ^ (l & 7)) << 3) | (k & 7))] = f2bf(v);
    }
}

// ---------------- fused SSM (chunked scan, MFMA, 48KB LDS, per-wave f32 scratch): zT -> yT ----------------
__global__ __launch_bounds__(256, 3) void ssm_kernel(const unsigned short* __restrict__ zT,
                                                     const unsigned short* __restrict__ tv,
                                                     const unsigned short* __restrict__ eb,
                                                     const float* __restrict__ da64,
                                                     unsigned short* __restrict__ yT) {
    static __shared__ __align__(16) char LDSA[49152];
    ushort_t* Zl = (ushort_t*)LDSA;
    ushort_t* R1 = (ushort_t*)(LDSA + 16384);
    ushort_t* R2 = (ushort_t*)(LDSA + 32768);
    ushort_t* YBl = (ushort_t*)(LDSA + 16384);
    int tid = threadIdx.x;
    int lane = tid & 63, wv = tid >> 6;
    int lr = lane & 15, lg = lane >> 4;
    int h = blockIdx.x, mb = blockIdx.y;

    float ar = da64[h * 128 + lane];
    float ai = da64[h * 128 + 64 + lane];

#pragma unroll
    for (int it = 0; it < 4; ++it) {
        int c = it * 256 + tid;
        int r = c >> 3, s = c & 7;
        int b = mb * 4 + (r >> 5), tile = r & 31;
        size_t src = ((size_t)(b * 256 + h) << 11) + tile * 64 + s * 8;
        gload16(zT + src, (char*)Zl + (it * 256 + wv * 64) * 16);
    }
#pragma unroll
    for (int it = 0; it < 4; ++it) {
        size_t src = (size_t)h * 24576 + (size_t)(it * 256 + tid) * 8;
        gload16(tv + src, (char*)R1 + (it * 256 + wv * 64) * 16);
    }
#pragma unroll
    for (int it = 0; it < 4; ++it) {
        size_t src = (size_t)h * 24576 + 8192 + (size_t)(it * 256 + tid) * 8;
        gload16(tv + src, (char*)R2 + (it * 256 + wv * 64) * 16);
    }
    __syncthreads();   // B1

    bf16x8 afz[2][2];
#pragma unroll
    for (int kk = 0; kk < 2; ++kk) {
        int row0 = wv * 32 + lr;
        int row1 = row0 + 16;
        afz[kk][0] = *(const bf16x8*)(Zl + row0 * 64 + (((kk * 4 + lg) ^ (row0 & 7)) << 3));
        afz[kk][1] = *(const bf16x8*)(Zl + row1 * 64 + (((kk * 4 + lg) ^ (row1 & 7)) << 3));
    }

    f32x4 y1[2][4], ua[2][8];
    f32x4 zf = {0.f, 0.f, 0.f, 0.f};
#pragma unroll
    for (int i = 0; i < 2; ++i) {
#pragma unroll
        for (int j = 0; j < 4; ++j) y1[i][j] = zf;
#pragma unroll
        for (int j = 0; j < 8; ++j) ua[i][j] = zf;
    }

#pragma unroll
    for (int kk = 0; kk < 2; ++kk) {
#pragma unroll
        for (int j = 0; j < 8; ++j) {
            int rw = (j < 4) ? ((j & 3) * 16 + lr) : (64 + (j & 3) * 16 + lr);
            bf16x8 bfr = *(const bf16x8*)(R1 + rw * 64 + (((kk * 4 + lg) ^ (lr & 7)) << 3));
            y1[0][j & 3] = __builtin_amdgcn_mfma_f32_16x16x32_bf16(afz[kk][0], bfr, y1[0][j & 3], 0, 0, 0);
            y1[1][j & 3] = __builtin_amdgcn_mfma_f32_16x16x32_bf16(afz[kk][1], bfr, y1[1][j & 3], 0, 0, 0);
        }
#pragma unroll
        for (int j = 0; j < 8; ++j) {
            int rw = (j < 4) ? ((j & 3) * 16 + lr) : (64 + (j & 3) * 16 + lr);
            bf16x8 bfr = *(const bf16x8*)(R2 + rw * 64 + (((kk * 4 + lg) ^ (lr & 7)) << 3));
            ua[0][j] = __builtin_amdgcn_mfma_f32_16x16x32_bf16(afz[kk][0], bfr, ua[0][j], 0, 0, 0);
            ua[1][j] = __builtin_amdgcn_mfma_f32_16x16x32_bf16(afz[kk][1], bfr, ua[1][j], 0, 0, 0);
        }
    }
    __syncthreads();   // B2

#pragma unroll
    for (int it = 0; it < 4; ++it) {
        size_t src = (size_t)h * 24576 + 16384 + (size_t)(it * 256 + tid) * 8;
        gload16(tv + src, (char*)R1 + (it * 256 + wv * 64) * 16);
    }
#pragma unroll
    for (int it = 0; it < 4; ++it) {
        size_t src = (size_t)h * 8192 + (size_t)(it * 256 + tid) * 8;
        gload16(eb + src, (char*)Zl + (it * 256 + wv * 64) * 16);
    }
    __syncthreads();   // B3

#pragma unroll
    for (int kk = 0; kk < 2; ++kk)
#pragma unroll
        for (int j = 0; j < 8; ++j) {
            int rw = (j < 4) ? ((j & 3) * 16 + lr) : (64 + (j & 3) * 16 + lr);
            bf16x8 bfr = *(const bf16x8*)(R1 + rw * 64 + (((kk * 4 + lg) ^ (lr & 7)) << 3));
            ua[0][j] = __builtin_amdgcn_mfma_f32_16x16x32_bf16(afz[kk][0], bfr, ua[0][j], 0, 0, 0);
            ua[1][j] = __builtin_amdgcn_mfma_f32_16x16x32_bf16(afz[kk][1], bfr, ua[1][j], 0, 0, 0);
        }
    __syncthreads();   // B4

    uint32* Su = (uint32*)(LDSA + 16384 + wv * 8192);
    bf16x8 afr[2][4];
    float Sre = 0.0f, Sim = 0.0f;
#pragma unroll
    for (int i = 0; i < 2; ++i) {
#pragma unroll
        for (int jj = 0; jj < 8; ++jj)
#pragma unroll
            for (int r = 0; r < 4; ++r) {
                int row = lg * 4 + r;
                int col = (jj & 3) * 16 + lr + ((jj >> 2) << 6);
                Su[row * 128 + (col ^ ((row & 7) << 2))] = __float_as_uint(ua[i][jj][r]);
            }
#pragma unroll
        for (int r = 0; r < 16; ++r) {
            int sx = (r & 7) << 2;
            int aRe = r * 128 + (lane ^ sx);
            int aIm = r * 128 + ((64 + lane) ^ sx);
            float ur = __uint_as_float(Su[aRe]);
            float ui = __uint_as_float(Su[aIm]);
            Su[aRe] = (uint32)f2bf(Sre);
            Su[aIm] = (uint32)f2bf(Sim);
            float nr = fmaf(ar, Sre, fmaf(-ai, Sim, ur));
            float ni = fmaf(ar, Sim, fmaf(ai, Sre, ui));
            Sre = nr; Sim = ni;
        }
#pragma unroll
        for (int kk = 0; kk < 4; ++kk) {
            int base = kk * 32 + lg * 8;
            int sx = (lr & 7) << 2;
            uint4 ua4 = *(const uint4*)&Su[lr * 128 + (base ^ sx)];
            uint4 ub4 = *(const uint4*)&Su[lr * 128 + ((base + 4) ^ sx)];
            uint4 pk;
            pk.x = __builtin_amdgcn_perm(ua4.y, ua4.x, 0x05040100u);
            pk.y = __builtin_amdgcn_perm(ua4.w, ua4.z, 0x05040100u);
            pk.z = __builtin_amdgcn_perm(ub4.y, ub4.x, 0x05040100u);
            pk.w = __builtin_amdgcn_perm(ub4.w, ub4.z, 0x05040100u);
            afr[i][kk] = *(bf16x8*)&pk;
        }
    }
    __syncthreads();   // B5

    f32x4 y2[2][4];
#pragma unroll
    for (int i = 0; i < 2; ++i)
#pragma unroll
        for (int j = 0; j < 4; ++j) y2[i][j] = zf;
#pragma unroll
    for (int kk = 0; kk < 4; ++kk)
#pragma unroll
        for (int j = 0; j < 4; ++j) {
            int rw = j * 16 + lr;
            bf16x8 bfr = *(const bf16x8*)(Zl + rw * 128 + (((kk * 4 + lg) ^ (rw & 7)) << 3));
            y2[0][j] = __builtin_amdgcn_mfma_f32_16x16x32_bf16(afr[0][kk], bfr, y2[0][j], 0, 0, 0);
            y2[1][j] = __builtin_amdgcn_mfma_f32_16x16x32_bf16(afr[1][kk], bfr, y2[1][j], 0, 0, 0);
        }

#pragma unroll
    for (int i = 0; i < 2; ++i)
#pragma unroll
        for (int j = 0; j < 4; ++j)
#pragma unroll
            for (int r = 0; r < 4; ++r) {
                int row = wv * 32 + i * 16 + lg * 4 + r;
                int col = j * 16 + lr;
                float y = y1[i][j][r] + y2[i][j][r];
                YBl[row * 72 + col] = f2bf(gelu_(y));
            }
    __syncthreads();   // B6

#pragma unroll
    for (int it = 0; it < 4; ++it) {
        int c = it * 256 + tid;
        int row = c >> 3, c8 = c & 7;
        int b = mb * 4 + (row >> 5), tile = row & 31;
        uint4 v = *(const uint4*)((const char*)YBl + row * 144 + c8 * 16);
        *(uint4*)(yT + (((size_t)(b * 256 + h)) << 11) + tile * 64 + c8 * 8) = v;
    }
}

// ---------------- gated MFMA GEMM + residual + FUSED LayerNorm -> zT (next layer) ----------------
// M=64 tokens x N=256 channels per block (grid 512); 4 waves, wave wv owns g-slice [64wv,64wv+64).
// A staged subtiled [hblk 8][tc 4] x [4h][16t]; frags via ds_read_b64_tr_b16 (verified layout).
__global__ __launch_bounds__(256, 2) void gatedln_kernel(const unsigned short* __restrict__ yT,
                                                         const unsigned short* __restrict__ w1b,
                                                         const unsigned short* __restrict__ w2b,
                                                         const float* __restrict__ b1,
                                                         const float* __restrict__ b2,
                                                         float* __restrict__ h,
                                                         const float* __restrict__ lnsc,
                                                         const float* __restrict__ lnbi,
                                                         uint32* __restrict__ zT_u,
                                                         int do_ln) {
    static __shared__ __align__(16) char GL[39424];
    ushort_t* Al = (ushort_t*)GL;                 // 4KB
    ushort_t* W1l = (ushort_t*)(GL + 4096);       // 16KB
    ushort_t* W2l = (ushort_t*)(GL + 20480);      // 16KB
    uint32* zb = (uint32*)GL;                     // [256][36] u32 overlay (36KB)
    float* psum = (float*)(GL + 36864);           // [64][4]
    float* psq = (float*)(GL + 36864 + 1024);     // [64][4]
    float* musab = (float*)(GL + 38912);          // [128]

    int tid = threadIdx.x;
    int lane = tid & 63;
    int wv = tid >> 6;
    int lr = lane & 15, lg = lane >> 4;
    size_t t0 = (size_t)blockIdx.x * 64;
    int bsel = (int)(t0 >> 11);
    int tloc0 = (int)(t0 & 2047);

    f32x4 acc1[4][4], acc2[4][4];
    f32x4 zf = {0.f, 0.f, 0.f, 0.f};
#pragma unroll
    for (int i = 0; i < 4; ++i)
#pragma unroll
        for (int j = 0; j < 4; ++j) { acc1[i][j] = zf; acc2[i][j] = zf; }

    uint32 abase = (uint32)(size_t)(__attribute__((address_space(3))) unsigned short*)Al;

    for (int kt = 0; kt < 8; ++kt) {
        __syncthreads();
        int k0 = kt * 32;
        // A: 256 slots (one per thread), blocks [hblk 8][tc 4] of [4h][16t]
        {
            int bi = tid >> 3, w = tid & 7;
            int hblk = bi >> 2, tc = bi & 3;
            int ha = hblk * 4 + (w >> 1);
            int toff = tc * 16 + (w & 1) * 8;
            gload16(yT + (((size_t)(bsel * 256 + k0 + ha)) << 11) + tloc0 + toff,
                    (char*)Al + (wv * 64) * 16);
        }
        // W1/W2: 1024 slots each, paired-row ^(L&7) swizzle in source
#pragma unroll
        for (int p = 0; p < 4; ++p) {
            int s = p * 256 + tid;
            int ldsoff = (p * 256 + wv * 64) * 16;
            int L = s >> 3, cs = s & 7;
            int cu = cs ^ (L & 7);
            int row = L * 2 + (cu >> 2), q = cu & 3;
            gload16(w1b + (size_t)row * 256 + k0 + q * 8, (char*)W1l + ldsoff);
            gload16(w2b + (size_t)row * 256 + k0 + q * 8, (char*)W2l + ldsoff);
        }
        __syncthreads();
        bf16x8 a[4], f1[4], f2[4];
#pragma unroll
        for (int i = 0; i < 4; ++i) {
            int tc = i;
            uint32 a0 = abase + (uint32)(((lg * 2 * 4 + tc) * 128) + lr * 8);
            uint32 a1 = a0 + 512;   // next hblk (4 blocks x 128B)
            uint2 d0, d1;
            asm volatile("ds_read_b64_tr_b16 %0, %2\n\t"
                         "ds_read_b64_tr_b16 %1, %3\n\t"
                         "s_waitcnt lgkmcnt(0)"
                         : "=&v"(d0), "=&v"(d1)
                         : "v"(a0), "v"(a1));
            uint4 pk;
            pk.x = d0.x; pk.y = d0.y; pk.z = d1.x; pk.w = d1.y;
            a[i] = *(bf16x8*)&pk;
        }
#pragma unroll
        for (int j = 0; j < 4; ++j) {
            int row = wv * 64 + j * 16 + lr;
            int wadr = (row >> 1) * 64 + ((((row & 1) * 4 + lg) ^ ((row >> 1) & 7)) << 3);
            f1[j] = *(const bf16x8*)(W1l + wadr);
            f2[j] = *(const bf16x8*)(W2l + wadr);
        }
#pragma unroll
        for (int i = 0; i < 4; ++i)
#pragma unroll
            for (int j = 0; j < 4; ++j) {
                acc1[i][j] = __builtin_amdgcn_mfma_f32_16x16x32_bf16(a[i], f1[j], acc1[i][j], 0, 0, 0);
                acc2[i][j] = __builtin_amdgcn_mfma_f32_16x16x32_bf16(a[i], f2[j], acc2[i][j], 0, 0, 0);
            }
    }
    __syncthreads();   // staging LDS dead; safe to overlay

    float bb1[4], bb2[4], scv[4], biv[4];
#pragma unroll
    for (int j = 0; j < 4; ++j) {
        int g = wv * 64 + j * 16 + lr;
        bb1[j] = b1[g];
        bb2[j] = b2[g];
        if (do_ln) { scv[j] = lnsc[g]; biv[j] = lnbi[g]; }
    }

    // gate + residual; keep h_new in acc1; accumulate LN partials
#pragma unroll
    for (int i = 0; i < 4; ++i)
#pragma unroll
        for (int r = 0; r < 4; ++r) {
            int row = i * 16 + lg * 4 + r;
            size_t t = t0 + row;
            float srow = 0.0f, qrow = 0.0f;
#pragma unroll
            for (int j = 0; j < 4; ++j) {
                int g = wv * 64 + j * 16 + lr;
                float p1 = acc1[i][j][r] + bb1[j];
                float p2 = acc2[i][j][r] + bb2[j];
                float* hp = &h[t * Hh + g];
                float hv = fmaf(p1, sigmoidf_(p2), *hp);
                *hp = hv;
                acc1[i][j][r] = hv;
                srow += hv;
                qrow = fmaf(hv, hv, qrow);
            }
            if (do_ln) {
                srow += __shfl_xor(srow, 1, 64); qrow += __shfl_xor(qrow, 1, 64);
                srow += __shfl_xor(srow, 2, 64); qrow += __shfl_xor(qrow, 2, 64);
                srow += __shfl_xor(srow, 4, 64); qrow += __shfl_xor(qrow, 4, 64);
                srow += __shfl_xor(srow, 8, 64); qrow += __shfl_xor(qrow, 8, 64);
                if (lr == 0) { psum[row * 4 + wv] = srow; psq[row * 4 + wv] = qrow; }
            }
        }

    if (do_ln) {
        __syncthreads();
        if (tid < 64) {
            float s = (psum[tid * 4] + psum[tid * 4 + 1]) + (psum[tid * 4 + 2] + psum[tid * 4 + 3]);
            float q = (psq[tid * 4] + psq[tid * 4 + 1]) + (psq[tid * 4 + 2] + psq[tid * 4 + 3]);
            float mu = s * (1.0f / 256.0f);
            float var = q * (1.0f / 256.0f) - mu * mu;
            musab[tid] = mu;
            musab[64 + tid] = rsqrtf(var + 1e-5f);
        }
        __syncthreads();
        // z = (h_new - mu)*rs*sc + bi -> zb[g][t/2] (u32 pairs), stride 36
#pragma unroll
        for (int i = 0; i < 4; ++i)
#pragma unroll
            for (int j = 0; j < 4; ++j) {
                int g = wv * 64 + j * 16 + lr;
                int row0 = i * 16 + lg * 4;
                float z0 = fmaf((acc1[i][j][0] - musab[row0]) * musab[64 + row0], scv[j], biv[j]);
                float z1 = fmaf((acc1[i][j][1] - musab[row0 + 1]) * musab[64 + row0 + 1], scv[j], biv[j]);
                float z2 = fmaf((acc1[i][j][2] - musab[row0 + 2]) * musab[64 + row0 + 2], scv[j], biv[j]);
                float z3 = fmaf((acc1[i][j][3] - musab[row0 + 3]) * musab[64 + row0 + 3], scv[j], biv[j]);
                zb[g * 36 + i * 8 + lg * 2 + 0] = ((uint32)f2bf(z1) << 16) | (uint32)f2bf(z0);
                zb[g * 36 + i * 8 + lg * 2 + 1] = ((uint32)f2bf(z3) << 16) | (uint32)f2bf(z2);
            }
        __syncthreads();
        // flush to zT with ssm chunk swizzle baked in
        int tile7 = (int)((t0 >> 6) & 7);
#pragma unroll
        for (int it = 0; it < 8; ++it) {
            int s2 = it * 256 + tid;
            int g2 = s2 >> 3, c = s2 & 7;
            uint4 v = *(const uint4*)&zb[g2 * 36 + c * 4];
            int csw = c ^ tile7;
            *(uint4*)(zT_u + (size_t)(bsel * 256 + g2) * 1024 + (tloc0 >> 1) + csw * 4) = v;
        }
    }
}

// ---------------- decoder ----------------
__global__ __launch_bounds__(256) void dec_kernel(const float* __restrict__ h,
                                                  const float* __restrict__ dec_w,
                                                  const float* __restrict__ dec_b,
                                                  float* __restrict__ out) {
    __shared__ float wT[256][36];
    __shared__ float hs[64][20];
    int tid = threadIdx.x;
    for (int idx = tid; idx < OUTD * Hh; idx += 256) {
        int o = idx >> 8, k = idx & 255;
        wT[k][o] = dec_w[idx];
    }
    size_t t0 = (size_t)blockIdx.x * 64;
    int tl = tid & 63, og = tid >> 6;
    float acc[9];
#pragma unroll
    for (int j = 0; j < 9; ++j) acc[j] = 0.0f;
    int i = tid >> 2, c = (tid & 3) * 4;
    for (int kt = 0; kt < 16; ++kt) {
        __syncthreads();
        *(float4*)&hs[i][c] = *(const float4*)&h[(t0 + i) * Hh + kt * 16 + c];
        __syncthreads();
#pragma unroll
        for (int k2 = 0; k2 < 16; ++k2) {
            float a = hs[tl][k2];
            int kk = kt * 16 + k2;
#pragma unroll
            for (int j = 0; j < 9; ++j) acc[j] = fmaf(a, wT[kk][og + 4 * j], acc[j]);
        }
    }
#pragma unroll
    for (int j = 0; j < 9; ++j) {
        int o = og + 4 * j;
        if (o < OUTD) out[(t0 + tl) * OUTD + o] = acc[j] + dec_b[o];
    }
}

extern "C" void kernel_launch(void* const* d_in, const int* in_sizes, int n_in,
                              void* d_out, int out_size, void* d_ws, size_t ws_size,
                              hipStream_t stream) {
    const float* x = (const float*)d_in[0];
    const float* enc_w = (const float*)d_in[1];
    const float* enc_b = (const float*)d_in[2];
    const float* lre = (const float*)d_in[3];
    const float* lim = (const float*)d_in[4];
    const float* cre = (const float*)d_in[5];
    const float* cim = (const float*)d_in[6];
    const float* dd = (const float*)d_in[7];
    const float* ls = (const float*)d_in[8];
    const float* lns = (const float*)d_in[9];
    const float* lnb = (const float*)d_in[10];
    const float* w1 = (const float*)d_in[11];
    const float* b1 = (const float*)d_in[12];
    const float* w2 = (const float*)d_in[13];
    const float* b2 = (const float*)d_in[14];
    const float* dw = (const float*)d_in[15];
    const float* db = (const float*)d_in[16];
    float* out = (float*)d_out;

    const size_t NTOK = (size_t)Bb * Lq;
    float* hbuf = (float*)d_ws;                                   // 32MB fp32
    unsigned short* zT = (unsigned short*)(hbuf + NTOK * Hh);     // 16MB bf16 [b][h][t] (swizzled chunks)
    unsigned short* yT = zT + NTOK * Hh;                          // 16MB bf16 [b][h][t] (linear)
    unsigned short* wbf = yT + NTOK * Hh;                         // 1MB bf16 gated weights
    unsigned short* tv_slab = wbf + 524288;                       // 4 layers x 6291456 ush = 50MB
    unsigned short* eb_slab = tv_slab + (size_t)4 * 6291456;      // 4 x 2097152 ush = 17MB
    float* da64 = (float*)(eb_slab + (size_t)4 * 2097152);        // 4 x 32768 f32

    wconv_kernel<<<128, 256, 0, stream>>>(w1, w2, wbf);
    enc_kernel<<<(int)(NTOK / 8), 256, 0, stream>>>(x, enc_w, enc_b, hbuf);
    k1_kernel<<<1024, 256, 0, stream>>>(lre, lim, cre, cim, dd, ls,
                                        tv_slab, eb_slab, da64);
    lnt_kernel<<<(int)(NTOK / 32), 256, 0, stream>>>(hbuf, lns, lnb, (uint32*)zT);
    for (int il = 0; il < NLay; ++il) {
        ssm_kernel<<<dim3(256, 4), 256, 0, stream>>>(zT,
                                                     tv_slab + (size_t)il * 6291456,
                                                     eb_slab + (size_t)il * 2097152,
                                                     da64 + (size_t)il * 32768, yT);
        int nl = (il < NLay - 1) ? (il + 1) : il;   // LN params of next layer (unused when do_ln=0)
        gatedln_kernel<<<(int)(NTOK / 64), 256, 0, stream>>>(
            yT, wbf + il * 65536, wbf + 262144 + il * 65536,
            b1 + il * Hh, b2 + il * Hh, hbuf,
            lns + nl * Hh, lnb + nl * Hh, (uint32*)zT,
            (il < NLay - 1) ? 1 : 0);
    }
    dec_kernel<<<(int)(NTOK / 64), 256, 0, stream>>>(hbuf, dw, db, out);
}